// Round 8
// baseline (178.807 us; speedup 1.0000x reference)
//
#include <hip/hip_runtime.h>

#define CIN   512
#define COUT  256
#define HWDIM 32
#define NBATCH 64
#define PIX_PER_IMG (HWDIM * HWDIM)          // 1024
#define NPIX (NBATCH * PIX_PER_IMG)          // 65536

typedef __attribute__((ext_vector_type(4))) int i32x4;

// ---------------- workspace layout ----------------
#define OFF_XB    ((size_t)0)
#define OFF_WB    ((size_t)33554432)
#define OFF_CONV  ((size_t)34734080)
#define OFF_STATS ((size_t)68288512)         // sum[8][256] i32 (8192) + sumsq[8][256] u64 (16384)
#define OFF_SCALE (OFF_STATS + 24576)
#define OFF_SHIFT (OFF_SCALE + 1024)
#define OFF_ZERO  (OFF_SHIFT + 1024)         // 1024 B zero page (covers sw + ci0 reach = 496 B)

// ---------------- pack x: f32 NCHW -> int8 sign NHWC ----------------
__global__ __launch_bounds__(256) void pack_x_kernel(const float* __restrict__ x,
                                                     signed char* __restrict__ xb) {
  const int plane = blockIdx.x;            // n*32 + h, 2048 planes
  const int n = plane >> 5, h = plane & 31;
  __shared__ int tile[HWDIM * 130];        // [w][130] ints (4 ci-bytes each)
  const int t = threadIdx.x;
  const float* xp = x + (size_t)n * CIN * PIX_PER_IMG + (size_t)h * HWDIM;
#define SB(v) ((v) >= 0.f ? 0x01u : 0xFFu)
#pragma unroll
  for (int it = 0; it < 4; ++it) {
    int idx = it * 256 + t;                // 0..1023
    int cib = idx >> 3;                    // ci block 0..127 (ci = cib*4)
    int w4 = (idx & 7) << 2;               // 0,4,...,28
    const float* p0 = xp + (size_t)(cib * 4 + 0) * PIX_PER_IMG + w4;
    float4 fa = *reinterpret_cast<const float4*>(p0);
    float4 fb = *reinterpret_cast<const float4*>(p0 + PIX_PER_IMG);
    float4 fc = *reinterpret_cast<const float4*>(p0 + 2 * PIX_PER_IMG);
    float4 fd = *reinterpret_cast<const float4*>(p0 + 3 * PIX_PER_IMG);
    unsigned o0 = SB(fa.x) | (SB(fb.x) << 8) | (SB(fc.x) << 16) | (SB(fd.x) << 24);
    unsigned o1 = SB(fa.y) | (SB(fb.y) << 8) | (SB(fc.y) << 16) | (SB(fd.y) << 24);
    unsigned o2 = SB(fa.z) | (SB(fb.z) << 8) | (SB(fc.z) << 16) | (SB(fd.z) << 24);
    unsigned o3 = SB(fa.w) | (SB(fb.w) << 8) | (SB(fc.w) << 16) | (SB(fd.w) << 24);
    tile[(w4 + 0) * 130 + cib] = (int)o0;
    tile[(w4 + 1) * 130 + cib] = (int)o1;
    tile[(w4 + 2) * 130 + cib] = (int)o2;
    tile[(w4 + 3) * 130 + cib] = (int)o3;
  }
  __syncthreads();
  int2* xo = reinterpret_cast<int2*>(xb + (size_t)plane * (HWDIM * CIN));
#pragma unroll
  for (int it = 0; it < 8; ++it) {
    int cc = it * 256 + t;                 // 8B chunk id 0..2047
    int w = cc >> 6, c8 = cc & 63;
    int2 v = make_int2(tile[w * 130 + c8 * 2], tile[w * 130 + c8 * 2 + 1]);
    xo[cc] = v;
  }
}

// ---------------- pack W: f32 OIHW -> int8 sign [tap][co][ci] ----------------
__global__ __launch_bounds__(256) void pack_w_kernel(const float* __restrict__ W,
                                                     signed char* __restrict__ wb) {
  int idx = blockIdx.x * 256 + threadIdx.x;     // 9*256*512 total
  int tap = idx / (COUT * CIN);
  int rem = idx - tap * (COUT * CIN);
  int co = rem >> 9;
  int ci = rem & 511;
  float v = W[((size_t)co * CIN + ci) * 9 + tap];
  wb[idx] = v >= 0.f ? 1 : -1;
}

// ---------------- conv: i8 MFMA GEMM, BK=128, ring-2, tap-outer ----------------
#define BM 256
#define BK 128
#define NSTEP 36                     // 4608 / 128; 4 steps per tap
#define ABYTES (BM * BK)             // 32768
#define BUFB   (2 * ABYTES)          // 65536 (A + B halves)
#define LDS_TOTAL (2 * BUFB)         // 131072
#define TAPB (COUT * CIN)            // 131072 B per tap of wb

__device__ __forceinline__ void load16(const void* g, void* l) {
  __builtin_amdgcn_global_load_lds((const __attribute__((address_space(1))) void*)g,
                                   (__attribute__((address_space(3))) void*)l, 16, 0, 0);
}

__global__ __launch_bounds__(512, 2) void conv_kernel(
    const signed char* __restrict__ xb,    // [2048][32][512]
    const signed char* __restrict__ wb,    // [9][256][512]
    short* __restrict__ cv,                // [64][256][1024]
    const signed char* __restrict__ zp,
    int* __restrict__ sum,                 // [8][256] shadows
    unsigned long long* __restrict__ sumsq) {
  extern __shared__ signed char lds[];       // 128 KB, 2 buffers of 64 KB
  const int t = threadIdx.x;
  const int wid = t >> 6, lane = t & 63;
  const int b = blockIdx.x;                  // 0..255, one per CU
  const int nimg = b >> 2;
  const int h0 = (b & 3) * 8;                // 8 image rows per block

  const int wr = wid >> 2;                   // 0..1   (M dir, 128 rows each)
  const int wc = wid & 3;                    // 0..3   (N dir, 64 cols each)

  i32x4 acc[8][4];
#pragma unroll
  for (int m = 0; m < 8; ++m)
#pragma unroll
    for (int n = 0; n < 4; ++n) { i32x4 z = {0, 0, 0, 0}; acc[m][n] = z; }

  // per-thread staging chunks: 4 A-chunks + 4 B-chunks, 16 B each.
  // chunk c: row r = c>>3, slot = c&7 (8 x 16B per 128-B row), source slot
  // pre-swizzled (slot ^ row&7) so linear LDS dest + swizzled read match.
  auto abase = [&](int tap, int c) -> const signed char* {
    int r = c >> 3;
    int sw = ((c & 7) ^ (r & 7)) << 4;
    int dh = tap / 3 - 1, dw = tap % 3 - 1;
    int hs = h0 + (r >> 5) + dh;
    int ws2 = (r & 31) + dw;
    bool ok = ((unsigned)hs < 32u) && ((unsigned)ws2 < 32u);
    return ok ? xb + ((size_t)((nimg * 32 + hs) * 32 + ws2) * CIN) + sw
              : zp + sw;
  };

  const signed char* pa[4];
  const signed char* pb[4];
#pragma unroll
  for (int it = 0; it < 4; ++it) {
    int c = it * 512 + t;
    pa[it] = abase(0, c);
    int co = c >> 3;
    pb[it] = wb + (size_t)co * CIN + (((c & 7) ^ (co & 7)) << 4);
  }

  // read-side frag offsets (k=0 slice; k=1 is byte^64)
  const int e = lane & 7;
  const int q = lane >> 4;
  const int slot0 = (q ^ e) << 4;
  int aoff[8], boff[4];
#pragma unroll
  for (int m = 0; m < 8; ++m) {
    int row = wr * 128 + m * 16 + (lane & 15);
    aoff[m] = row * BK + slot0;
  }
#pragma unroll
  for (int n = 0; n < 4; ++n) {
    int col = wc * 64 + n * 16 + (lane & 15);
    boff[n] = ABYTES + col * BK + slot0;
  }

  auto stage = [&](int buf, const signed char* const* ppa,
                   const signed char* const* ppb, int ci0) {
    signed char* dst = lds + buf * BUFB;
#pragma unroll
    for (int it = 0; it < 4; ++it) {
      int c = it * 512 + t;
      load16(ppa[it] + ci0, (void*)(dst + c * 16));
      load16(ppb[it] + ci0, (void*)(dst + ABYTES + c * 16));
    }
  };

  // prologue: stage step 0 into buf 0
  stage(0, pa, pb, 0);

  for (int tap = 0; tap < 9; ++tap) {
    // next-tap A bases (hoisted halo logic, amortized over 4 steps)
    const signed char* npa[4];
    if (tap < 8) {
#pragma unroll
      for (int it = 0; it < 4; ++it) npa[it] = abase(tap + 1, it * 512 + t);
    } else {
#pragma unroll
      for (int it = 0; it < 4; ++it) npa[it] = zp;
    }
#pragma unroll
    for (int j = 0; j < 4; ++j) {
      const int s = tap * 4 + j;
      // stage step s+1 into buf (s+1)&1 (depth-1 prefetch; a full compute
      // phase of ~2600 cyc covers the L2 latency)
      if (j < 3) {
        stage((s + 1) & 1, pa, pb, (j + 1) * BK);
      } else if (tap < 8) {
        const signed char* npb[4];
#pragma unroll
        for (int it = 0; it < 4; ++it) npb[it] = pb[it] + TAPB;
        stage((s + 1) & 1, npa, npb, 0);
      }
      if (s + 1 < NSTEP) asm volatile("s_waitcnt vmcnt(8)" ::: "memory");
      else               asm volatile("s_waitcnt vmcnt(0)" ::: "memory");
      __builtin_amdgcn_s_barrier();          // buf[s&1] fully written

      const signed char* base = lds + (s & 1) * BUFB;
      i32x4 af[8], bf[4];
      // k-slice 0
#pragma unroll
      for (int n = 0; n < 4; ++n)
        bf[n] = *reinterpret_cast<const i32x4*>(base + boff[n]);
#pragma unroll
      for (int m = 0; m < 8; ++m)
        af[m] = *reinterpret_cast<const i32x4*>(base + aoff[m]);
      __builtin_amdgcn_s_setprio(1);
#pragma unroll
      for (int m = 0; m < 8; ++m)
#pragma unroll
        for (int n = 0; n < 4; ++n)
          acc[m][n] = __builtin_amdgcn_mfma_i32_16x16x64_i8(af[m], bf[n], acc[m][n], 0, 0, 0);
      __builtin_amdgcn_s_setprio(0);
      // k-slice 1 (byte offsets ^64 under the slot swizzle)
#pragma unroll
      for (int n = 0; n < 4; ++n)
        bf[n] = *reinterpret_cast<const i32x4*>(base + (boff[n] ^ 64));
#pragma unroll
      for (int m = 0; m < 8; ++m)
        af[m] = *reinterpret_cast<const i32x4*>(base + (aoff[m] ^ 64));
      __builtin_amdgcn_s_setprio(1);
#pragma unroll
      for (int m = 0; m < 8; ++m)
#pragma unroll
        for (int n = 0; n < 4; ++n)
          acc[m][n] = __builtin_amdgcn_mfma_i32_16x16x64_i8(af[m], bf[n], acc[m][n], 0, 0, 0);
      __builtin_amdgcn_s_setprio(0);
      __builtin_amdgcn_s_barrier();          // all waves done reading buf[s&1]
    }
#pragma unroll
    for (int it = 0; it < 4; ++it) { pa[it] = npa[it]; pb[it] += TAPB; }
  }

  // epilogue A: write int16 conv output, NCHW
  const int P0 = b * BM;
#pragma unroll
  for (int m = 0; m < 8; ++m) {
#pragma unroll
    for (int n = 0; n < 4; ++n) {
      int row = wr * 128 + m * 16 + ((lane >> 4) << 2);
      int co = wc * 64 + n * 16 + (lane & 15);
      int P = P0 + row;
      int ni = P >> 10;
      int hw = P & 1023;
      short4 v = make_short4((short)acc[m][n][0], (short)acc[m][n][1],
                             (short)acc[m][n][2], (short)acc[m][n][3]);
      *reinterpret_cast<short4*>(cv + (((size_t)ni * COUT + co) << 10) + hw) = v;
    }
  }

  // epilogue B: fused per-channel sum / sumsq into 8 shadow copies (exact integers)
  int* sumS = sum + (b & 7) * COUT;
  unsigned long long* sqS = sumsq + (b & 7) * COUT;
#pragma unroll
  for (int n = 0; n < 4; ++n) {
    int s1 = 0;
    long long s2 = 0;
#pragma unroll
    for (int m = 0; m < 8; ++m)
#pragma unroll
      for (int j = 0; j < 4; ++j) {
        int v = acc[m][n][j];
        s1 += v;
        s2 += (long long)v * v;
      }
    s1 += __shfl_xor(s1, 16, 64);
    s1 += __shfl_xor(s1, 32, 64);
    s2 += __shfl_xor(s2, 16, 64);
    s2 += __shfl_xor(s2, 32, 64);
    if (lane < 16) {
      int c = wc * 64 + n * 16 + lane;
      atomicAdd(&sumS[c], s1);
      atomicAdd(&sqS[c], (unsigned long long)s2);
    }
  }
}

// ---------------- stats -> scale/shift (sums 8 shadows) ----------------
__global__ void stats_kernel(const int* __restrict__ sum,
                             const unsigned long long* __restrict__ sumsq,
                             const float* __restrict__ gamma,
                             const float* __restrict__ beta,
                             float* __restrict__ scale,
                             float* __restrict__ shift) {
  int co = threadIdx.x;
  long long s1 = 0, s2 = 0;
#pragma unroll
  for (int k = 0; k < 8; ++k) {
    s1 += sum[k * COUT + co];
    s2 += (long long)sumsq[k * COUT + co];
  }
  double cnt = (double)NPIX;
  double mean = (double)s1 / cnt;
  double ex2 = (double)s2 / cnt;
  double var = ex2 - mean * mean;
  double rs = 1.0 / sqrt(var + 1e-5);
  float g = gamma[co];
  scale[co] = (float)rs * g;
  shift[co] = beta[co] - (float)(mean * rs) * g;
}

// ---------------- normalize + residual + clip (8 elems/thread) ----------------
__global__ __launch_bounds__(256) void final_kernel(const short* __restrict__ cv,
                                                    const float* __restrict__ x,
                                                    const float* __restrict__ scale,
                                                    const float* __restrict__ shift,
                                                    float* __restrict__ out) {
  size_t i = ((size_t)blockIdx.x * 256 + threadIdx.x) * 8;
  int co = (int)((i >> 10) & 255);
  size_t n = i >> 18;
  size_t hw = i & 1023;
  short4 c0 = *reinterpret_cast<const short4*>(cv + i);
  short4 c1 = *reinterpret_cast<const short4*>(cv + i + 4);
  const float* xr = x + ((n * CIN + co) << 10) + hw;
  float4 r0 = *reinterpret_cast<const float4*>(xr);
  float4 r1 = *reinterpret_cast<const float4*>(xr + 4);
  float sc = scale[co], sh = shift[co];
  float4 o0, o1;
  o0.x = fminf(1.f, fmaxf(-1.f, (float)c0.x * sc + sh + r0.x));
  o0.y = fminf(1.f, fmaxf(-1.f, (float)c0.y * sc + sh + r0.y));
  o0.z = fminf(1.f, fmaxf(-1.f, (float)c0.z * sc + sh + r0.z));
  o0.w = fminf(1.f, fmaxf(-1.f, (float)c0.w * sc + sh + r0.w));
  o1.x = fminf(1.f, fmaxf(-1.f, (float)c1.x * sc + sh + r1.x));
  o1.y = fminf(1.f, fmaxf(-1.f, (float)c1.y * sc + sh + r1.y));
  o1.z = fminf(1.f, fmaxf(-1.f, (float)c1.z * sc + sh + r1.z));
  o1.w = fminf(1.f, fmaxf(-1.f, (float)c1.w * sc + sh + r1.w));
  *reinterpret_cast<float4*>(out + i) = o0;
  *reinterpret_cast<float4*>(out + i + 4) = o1;
}

extern "C" void kernel_launch(void* const* d_in, const int* in_sizes, int n_in,
                              void* d_out, int out_size, void* d_ws, size_t ws_size,
                              hipStream_t stream) {
  const float* x     = (const float*)d_in[0];
  const float* W     = (const float*)d_in[1];
  const float* gamma = (const float*)d_in[2];
  const float* beta  = (const float*)d_in[3];
  float* out = (float*)d_out;
  char* ws = (char*)d_ws;

  signed char* xb = (signed char*)(ws + OFF_XB);
  signed char* wb = (signed char*)(ws + OFF_WB);
  short* cv = (short*)(ws + OFF_CONV);
  int* sum = (int*)(ws + OFF_STATS);
  unsigned long long* sumsq = (unsigned long long*)(ws + OFF_STATS + 8192);
  float* scale = (float*)(ws + OFF_SCALE);
  float* shift = (float*)(ws + OFF_SHIFT);
  signed char* zp = (signed char*)(ws + OFF_ZERO);

  // allow 128 KB dynamic LDS (host-side metadata; capture-safe, idempotent)
  hipFuncSetAttribute((const void*)conv_kernel,
                      hipFuncAttributeMaxDynamicSharedMemorySize, LDS_TOTAL);

  // zero shadows + scale/shift + 1 KB zero page (27,648 B)
  hipMemsetAsync(ws + OFF_STATS, 0, 27648, stream);

  pack_x_kernel<<<NBATCH * HWDIM, 256, 0, stream>>>(x, xb);
  pack_w_kernel<<<(9 * COUT * CIN) / 256, 256, 0, stream>>>(W, wb);
  conv_kernel<<<NPIX / BM, 512, LDS_TOTAL, stream>>>(xb, wb, cv, zp, sum, sumsq);
  stats_kernel<<<1, 256, 0, stream>>>(sum, sumsq, gamma, beta, scale, shift);
  final_kernel<<<(NBATCH * COUT * PIX_PER_IMG) / (256 * 8), 256, 0, stream>>>(
      cv, x, scale, shift, out);
}

// Round 9
// 103.746 us; speedup vs baseline: 1.7235x; 1.7235x over previous
//
#include <hip/hip_runtime.h>

#define CIN   512
#define COUT  256
#define HWDIM 32
#define NBATCH 64
#define PIX_PER_IMG (HWDIM * HWDIM)          // 1024
#define NPIX (NBATCH * PIX_PER_IMG)          // 65536

typedef __attribute__((ext_vector_type(4))) int   i32x4;
typedef __attribute__((ext_vector_type(8))) int   i32x8;
typedef __attribute__((ext_vector_type(4))) float f32x4;

// ---------------- workspace layout ----------------
// xb4 : [65536 pixels][256 B]  fp4 signs, NHWC     16,777,216 B @ 0
// wb4 : [9][256][256 B]        fp4 signs              589,824 B @ 16,777,216
// cv  : [64][256][1024] int16                      33,554,432 B @ 17,367,040
// stats/scale/shift/zeropage                           27,648 B @ 50,921,472
#define OFF_XB4   ((size_t)0)
#define OFF_WB4   ((size_t)16777216)
#define OFF_CONV  ((size_t)17367040)
#define OFF_STATS ((size_t)50921472)
#define OFF_SCALE (OFF_STATS + 24576)
#define OFF_SHIFT (OFF_SCALE + 1024)
#define OFF_ZERO  (OFF_SHIFT + 1024)         // 1024 B zero page (fp4 0x00 = +0.0)

// fp4 e2m1: +1.0 = 0x2, -1.0 = 0xA
#define NIB(v) ((v) >= 0.f ? 0x2u : 0xAu)

// ---------------- pack x: f32 NCHW -> fp4 sign NHWC ----------------
__global__ __launch_bounds__(256) void pack_x4_kernel(const float* __restrict__ x,
                                                      unsigned char* __restrict__ xb4) {
  const int plane = blockIdx.x;            // n*32 + h, 2048 planes
  const int n = plane >> 5, h = plane & 31;
  __shared__ unsigned int tile[HWDIM * 66];   // [w][66] words of 8 ci-nibbles
  const int t = threadIdx.x;
  const float* xp = x + (size_t)n * CIN * PIX_PER_IMG + (size_t)h * HWDIM;
#pragma unroll
  for (int it = 0; it < 2; ++it) {
    int idx = it * 256 + t;                // 0..511
    int cib = idx >> 3;                    // 8-ci group 0..63
    int w4 = (idx & 7) << 2;               // 0,4,..,28
    unsigned n0 = 0, n1 = 0, n2 = 0, n3 = 0;
#pragma unroll
    for (int d = 0; d < 8; ++d) {
      float4 f = *reinterpret_cast<const float4*>(
          xp + (size_t)(cib * 8 + d) * PIX_PER_IMG + w4);
      n0 |= NIB(f.x) << (4 * d);
      n1 |= NIB(f.y) << (4 * d);
      n2 |= NIB(f.z) << (4 * d);
      n3 |= NIB(f.w) << (4 * d);
    }
    tile[(w4 + 0) * 66 + cib] = n0;
    tile[(w4 + 1) * 66 + cib] = n1;
    tile[(w4 + 2) * 66 + cib] = n2;
    tile[(w4 + 3) * 66 + cib] = n3;
  }
  __syncthreads();
  uint4* xo = reinterpret_cast<uint4*>(xb4 + (size_t)plane * (HWDIM * CIN / 2));
#pragma unroll
  for (int it = 0; it < 2; ++it) {
    int cc = it * 256 + t;                 // 16B chunk 0..511
    int w = cc >> 4, c4 = (cc & 15) << 2;
    uint4 v = make_uint4(tile[w * 66 + c4], tile[w * 66 + c4 + 1],
                         tile[w * 66 + c4 + 2], tile[w * 66 + c4 + 3]);
    xo[cc] = v;
  }
}

// ---------------- pack W: f32 OIHW -> fp4 sign [tap][co][ci/2] ----------------
__global__ __launch_bounds__(256) void pack_w4_kernel(const float* __restrict__ W,
                                                      unsigned int* __restrict__ wb4) {
  int idxu = blockIdx.x * 256 + threadIdx.x;    // u32 id, 9*256*64 = 147456 total
  int tap = idxu / (COUT * 64);
  int rem = idxu - tap * (COUT * 64);
  int co = rem >> 6;
  int ci0 = (rem & 63) << 3;
  unsigned nib = 0;
#pragma unroll
  for (int d = 0; d < 8; ++d) {
    float v = W[((size_t)co * CIN + ci0 + d) * 9 + tap];
    nib |= NIB(v) << (4 * d);
  }
  wb4[idxu] = nib;                          // layout [tap][co][64 words]
}

// ---------------- conv: MX-fp4 MFMA GEMM, ring-4, depth-3, tap-outer ----------
#define BM 256
#define BKB 64                       // bytes per row per step (= 128 fp4 elems)
#define ABYTES (BM * BKB)            // 16384
#define BUFB   (ABYTES + COUT * BKB) // 32768
#define LDS_TOTAL (4 * BUFB)         // 131072
#define TAPB4 (COUT * (CIN / 2))     // 65536 B per tap of wb4

__device__ __forceinline__ void load16(const void* g, void* l) {
  __builtin_amdgcn_global_load_lds((const __attribute__((address_space(1))) void*)g,
                                   (__attribute__((address_space(3))) void*)l, 16, 0, 0);
}

__device__ __forceinline__ i32x8 up8(i32x4 v) {
  i32x8 r;
  r[0] = v[0]; r[1] = v[1]; r[2] = v[2]; r[3] = v[3];
  r[4] = 0;    r[5] = 0;    r[6] = 0;    r[7] = 0;
  return r;
}

__global__ __launch_bounds__(512, 2) void conv_kernel(
    const unsigned char* __restrict__ xb4,   // [65536][256]
    const unsigned char* __restrict__ wb4,   // [9][256][256]
    short* __restrict__ cv,                  // [64][256][1024]
    const unsigned char* __restrict__ zp,
    int* __restrict__ sum,                   // [8][256] shadows
    unsigned long long* __restrict__ sumsq) {
  extern __shared__ signed char lds[];       // 128 KB, ring of 4
  const int t = threadIdx.x;
  const int wid = t >> 6, lane = t & 63;
  const int b = blockIdx.x;                  // 0..255
  const int nimg = b >> 2;
  const int h0 = (b & 3) * 8;

  const int wr = wid >> 2;                   // 0..1 (M)
  const int wc = wid & 3;                    // 0..3 (N)

  f32x4 acc[8][4];
#pragma unroll
  for (int m = 0; m < 8; ++m)
#pragma unroll
    for (int n = 0; n < 4; ++n) { f32x4 z = {0.f, 0.f, 0.f, 0.f}; acc[m][n] = z; }

  // per-tap base pointers; chunk c: row r=c>>2, slot=c&3, source pre-swizzled
  auto abase = [&](int tap, int c) -> const unsigned char* {
    int r = c >> 2;
    int sw = ((c & 3) ^ ((c >> 3) & 3)) << 4;
    int dh = tap / 3 - 1, dw = tap % 3 - 1;
    int hs = h0 + (r >> 5) + dh;
    int ws2 = (r & 31) + dw;
    bool ok = ((unsigned)hs < 32u) && ((unsigned)ws2 < 32u);
    return ok ? xb4 + (size_t)((nimg * 32 + hs) * 32 + ws2) * 256 + sw
              : zp + sw;
  };
  auto bbase = [&](int tap, int c) -> const unsigned char* {
    int co = c >> 2;
    int sw = ((c & 3) ^ ((c >> 3) & 3)) << 4;
    return wb4 + (size_t)tap * TAPB4 + (size_t)co * 256 + sw;
  };

  const int c0 = t, c1 = 512 + t;
  const unsigned char *a0 = abase(0, c0), *a1 = abase(0, c1);
  const unsigned char *b0 = bbase(0, c0), *b1 = bbase(0, c1);

  // read-side frag offsets (r7's verified 0-conflict swizzle; 64-B rows)
  const int koff = (lane >> 4) << 4;
  const int ksw  = (((lane >> 1) & 3) << 4);
  int aoff[8], boff[4];
#pragma unroll
  for (int m = 0; m < 8; ++m) {
    int row = wr * 128 + m * 16 + (lane & 15);
    aoff[m] = row * BKB + (koff ^ ksw);
  }
#pragma unroll
  for (int n = 0; n < 4; ++n) {
    int col = wc * 64 + n * 16 + (lane & 15);
    boff[n] = ABYTES + col * BKB + (koff ^ ksw);
  }

  auto stage = [&](int buf, const unsigned char* A0, const unsigned char* A1,
                   const unsigned char* B0, const unsigned char* B1, int off) {
    signed char* dst = lds + buf * BUFB;
    load16(A0 + off, (void*)(dst + c0 * 16));
    load16(A1 + off, (void*)(dst + c1 * 16));
    load16(B0 + off, (void*)(dst + ABYTES + c0 * 16));
    load16(B1 + off, (void*)(dst + ABYTES + c1 * 16));
  };

  // prologue: stage tap0 slices 0..2 into bufs 0..2 (depth-3)
  stage(0, a0, a1, b0, b1, 0);
  stage(1, a0, a1, b0, b1, 64);
  stage(2, a0, a1, b0, b1, 128);
  asm volatile("s_waitcnt vmcnt(8)" ::: "memory");   // buf0 ready
  __builtin_amdgcn_s_barrier();

  for (int tap = 0; tap < 9; ++tap) {
    const unsigned char *na0, *na1, *nb0, *nb1;
    if (tap < 8) {
      na0 = abase(tap + 1, c0); na1 = abase(tap + 1, c1);
      nb0 = b0 + TAPB4;         nb1 = b1 + TAPB4;
    } else {
      na0 = na1 = nb0 = nb1 = zp;
    }
#pragma unroll
    for (int j = 0; j < 4; ++j) {
      const int s = tap * 4 + j;
      if (j == 0)           stage((s + 3) & 3, a0, a1, b0, b1, 192);
      else if (tap < 8)     stage((s + 3) & 3, na0, na1, nb0, nb1, (j - 1) * 64);
      const signed char* base = lds + (s & 3) * BUFB;
      i32x4 af[8], bf[4];
#pragma unroll
      for (int n = 0; n < 4; ++n)
        bf[n] = *reinterpret_cast<const i32x4*>(base + boff[n]);
#pragma unroll
      for (int m = 0; m < 8; ++m)
        af[m] = *reinterpret_cast<const i32x4*>(base + aoff[m]);
      __builtin_amdgcn_s_setprio(1);
#pragma unroll
      for (int m = 0; m < 8; ++m)
#pragma unroll
        for (int n = 0; n < 4; ++n)
          acc[m][n] = __builtin_amdgcn_mfma_scale_f32_16x16x128_f8f6f4(
              up8(af[m]), up8(bf[n]), acc[m][n],
              4, 4,                  // cbsz=fp4, blgp=fp4
              0, 0x7F7F7F7Fu,        // opselA, scaleA = 1.0 (e8m0 127)
              0, 0x7F7F7F7Fu);       // opselB, scaleB
      __builtin_amdgcn_s_setprio(0);
      if (tap < 8 || j == 0) asm volatile("s_waitcnt vmcnt(8)" ::: "memory");
      else if (j == 1)       asm volatile("s_waitcnt vmcnt(4)" ::: "memory");
      else                   asm volatile("s_waitcnt vmcnt(0)" ::: "memory");
      __builtin_amdgcn_s_barrier();          // single barrier per step
    }
    a0 = na0; a1 = na1; b0 = nb0; b1 = nb1;
  }

  // epilogue A: int16 conv output, NCHW (acc floats are exact integers)
  const int P0 = b * BM;
#pragma unroll
  for (int m = 0; m < 8; ++m) {
#pragma unroll
    for (int n = 0; n < 4; ++n) {
      int row = wr * 128 + m * 16 + ((lane >> 4) << 2);
      int co = wc * 64 + n * 16 + (lane & 15);
      int P = P0 + row;
      int ni = P >> 10;
      int hw = P & 1023;
      short4 v = make_short4((short)(int)acc[m][n][0], (short)(int)acc[m][n][1],
                             (short)(int)acc[m][n][2], (short)(int)acc[m][n][3]);
      *reinterpret_cast<short4*>(cv + (((size_t)ni * COUT + co) << 10) + hw) = v;
    }
  }

  // epilogue B: fused per-channel sum / sumsq (exact integers), 8 shadows
  int* sumS = sum + (b & 7) * COUT;
  unsigned long long* sqS = sumsq + (b & 7) * COUT;
#pragma unroll
  for (int n = 0; n < 4; ++n) {
    int s1 = 0;
    long long s2 = 0;
#pragma unroll
    for (int m = 0; m < 8; ++m)
#pragma unroll
      for (int j = 0; j < 4; ++j) {
        int v = (int)acc[m][n][j];
        s1 += v;
        s2 += (long long)v * v;
      }
    s1 += __shfl_xor(s1, 16, 64);
    s1 += __shfl_xor(s1, 32, 64);
    s2 += __shfl_xor(s2, 16, 64);
    s2 += __shfl_xor(s2, 32, 64);
    if (lane < 16) {
      int c = wc * 64 + n * 16 + lane;
      atomicAdd(&sumS[c], s1);
      atomicAdd(&sqS[c], (unsigned long long)s2);
    }
  }
}

// ---------------- stats -> scale/shift (sums 8 shadows) ----------------
__global__ void stats_kernel(const int* __restrict__ sum,
                             const unsigned long long* __restrict__ sumsq,
                             const float* __restrict__ gamma,
                             const float* __restrict__ beta,
                             float* __restrict__ scale,
                             float* __restrict__ shift) {
  int co = threadIdx.x;
  long long s1 = 0, s2 = 0;
#pragma unroll
  for (int k = 0; k < 8; ++k) {
    s1 += sum[k * COUT + co];
    s2 += (long long)sumsq[k * COUT + co];
  }
  double cnt = (double)NPIX;
  double mean = (double)s1 / cnt;
  double ex2 = (double)s2 / cnt;
  double var = ex2 - mean * mean;
  double rs = 1.0 / sqrt(var + 1e-5);
  float g = gamma[co];
  scale[co] = (float)rs * g;
  shift[co] = beta[co] - (float)(mean * rs) * g;
}

// ---------------- normalize + residual + clip (8 elems/thread) ----------------
__global__ __launch_bounds__(256) void final_kernel(const short* __restrict__ cv,
                                                    const float* __restrict__ x,
                                                    const float* __restrict__ scale,
                                                    const float* __restrict__ shift,
                                                    float* __restrict__ out) {
  size_t i = ((size_t)blockIdx.x * 256 + threadIdx.x) * 8;
  int co = (int)((i >> 10) & 255);
  size_t n = i >> 18;
  size_t hw = i & 1023;
  short4 c0 = *reinterpret_cast<const short4*>(cv + i);
  short4 c1 = *reinterpret_cast<const short4*>(cv + i + 4);
  const float* xr = x + ((n * CIN + co) << 10) + hw;
  float4 r0 = *reinterpret_cast<const float4*>(xr);
  float4 r1 = *reinterpret_cast<const float4*>(xr + 4);
  float sc = scale[co], sh = shift[co];
  float4 o0, o1;
  o0.x = fminf(1.f, fmaxf(-1.f, (float)c0.x * sc + sh + r0.x));
  o0.y = fminf(1.f, fmaxf(-1.f, (float)c0.y * sc + sh + r0.y));
  o0.z = fminf(1.f, fmaxf(-1.f, (float)c0.z * sc + sh + r0.z));
  o0.w = fminf(1.f, fmaxf(-1.f, (float)c0.w * sc + sh + r0.w));
  o1.x = fminf(1.f, fmaxf(-1.f, (float)c1.x * sc + sh + r1.x));
  o1.y = fminf(1.f, fmaxf(-1.f, (float)c1.y * sc + sh + r1.y));
  o1.z = fminf(1.f, fmaxf(-1.f, (float)c1.z * sc + sh + r1.z));
  o1.w = fminf(1.f, fmaxf(-1.f, (float)c1.w * sc + sh + r1.w));
  *reinterpret_cast<float4*>(out + i) = o0;
  *reinterpret_cast<float4*>(out + i + 4) = o1;
}

extern "C" void kernel_launch(void* const* d_in, const int* in_sizes, int n_in,
                              void* d_out, int out_size, void* d_ws, size_t ws_size,
                              hipStream_t stream) {
  const float* x     = (const float*)d_in[0];
  const float* W     = (const float*)d_in[1];
  const float* gamma = (const float*)d_in[2];
  const float* beta  = (const float*)d_in[3];
  float* out = (float*)d_out;
  char* ws = (char*)d_ws;

  unsigned char* xb4 = (unsigned char*)(ws + OFF_XB4);
  unsigned char* wb4 = (unsigned char*)(ws + OFF_WB4);
  short* cv = (short*)(ws + OFF_CONV);
  int* sum = (int*)(ws + OFF_STATS);
  unsigned long long* sumsq = (unsigned long long*)(ws + OFF_STATS + 8192);
  float* scale = (float*)(ws + OFF_SCALE);
  float* shift = (float*)(ws + OFF_SHIFT);
  unsigned char* zp = (unsigned char*)(ws + OFF_ZERO);

  hipFuncSetAttribute((const void*)conv_kernel,
                      hipFuncAttributeMaxDynamicSharedMemorySize, LDS_TOTAL);

  // zero shadows + scale/shift + 1 KB zero page
  hipMemsetAsync(ws + OFF_STATS, 0, 27648, stream);

  pack_x4_kernel<<<NBATCH * HWDIM, 256, 0, stream>>>(x, xb4);
  pack_w4_kernel<<<(9 * COUT * 64) / 256, 256, 0, stream>>>(W, (unsigned int*)wb4);
  conv_kernel<<<NPIX / BM, 512, LDS_TOTAL, stream>>>(xb4, wb4, cv, zp, sum, sumsq);
  stats_kernel<<<1, 256, 0, stream>>>(sum, sumsq, gamma, beta, scale, shift);
  final_kernel<<<(NBATCH * COUT * PIX_PER_IMG) / (256 * 8), 256, 0, stream>>>(
      cv, x, scale, shift, out);
}